// Round 1
// baseline (5966.879 us; speedup 1.0000x reference)
//
#include <hip/hip_runtime.h>
#include <hip/hip_bf16.h>
#include <stdint.h>

// Problem constants
#define NB 128    // batch
#define NT 512    // time steps
#define ND 256    // input dim
#define NH 1024   // hidden dim
#define NZ 128    // latent dim
#define NG 4096   // 4*NH gate width

typedef __attribute__((ext_vector_type(8))) __bf16 bf16x8;
typedef __attribute__((ext_vector_type(4))) __bf16 bf16x4;
typedef __attribute__((ext_vector_type(4))) float floatx4;

// Fast native transcendentals (v_exp_f32 / v_log_f32 / v_rcp_f32).
__device__ __forceinline__ float fsigmoid_(float x) {
  return __fdividef(1.0f, 1.0f + __expf(-x));
}
__device__ __forceinline__ float fsoftplus_(float x) {
  return fmaxf(x, 0.0f) + __logf(1.0f + __expf(-fabsf(x)));
}

// B-fragment loader: 8 fp32 rows (stride NG) -> bf16x8
__device__ __forceinline__ bf16x8 load_bfrag(const float* s) {
  bf16x8 v;
#pragma unroll
  for (int jj = 0; jj < 8; ++jj) v[jj] = (__bf16)s[jj * NG];
  return v;
}

// ---------------------------------------------------------------------------
// Kernel 1: convert x (B,T,D) fp32 -> xb (T,B,D) bf16
// ---------------------------------------------------------------------------
__global__ __launch_bounds__(256) void convert_x_kernel(
    const float4* __restrict__ x, __bf16* __restrict__ xb) {
  int i = blockIdx.x * 256 + threadIdx.x;
  int d4 = i & 63;
  int bt = i >> 6;
  int b = bt >> 9;
  int t = bt & 511;
  float4 v = x[i];
  bf16x4 o;
  o[0] = (__bf16)v.x; o[1] = (__bf16)v.y; o[2] = (__bf16)v.z; o[3] = (__bf16)v.w;
  *(bf16x4*)(xb + ((t * NB + b) * ND + d4 * 4)) = o;
}

// ---------------------------------------------------------------------------
// Kernel 2: persistent LSTM — R10: dual-group pipelining.
// Grid 128 WGs x 512 thr (cooperative). WG = (p = wg&3, n_blk = wg>>2) and
// owns TWO independent batch groups: mA = p, mB = p+4, SAME n_blk (h-cols
// [n_blk*32,+32)) so all 40 W/U B-frags (160 VGPRs) are shared. The two
// recurrences interleave: while group A's h-broadcast makes its fabric round
// trip (publish->LLC->poll->gather), the WG computes group B, and vice versa.
// Communication cliques: group m's producers+consumers = the 32 WGs with
// wg&3 == m&3 — same 32-WG fan-in as R9.
//
// Per-wave flags replace {S3 + tid0 release}: wave wv publishes rows
// {2wv,2wv+1} of its group's h-tile, so its own vmcnt(0) drain suffices to
// release flag[(m*32+n)*8+wv]. The drain+release is DEFERRED into the
// opposite tile (after gather-issue + XPHASE) so it overlaps compute:
//   tile A(t) releases flag_b = t   (drains B(t-1) publishes)
//   tile B(t) releases flag_a = t+1 (drains A(t)   publishes)
// Induction grounds at t=0 (flags zeroed, hbuf half 0 zeroed). Consumers
// poll 32 contiguous per-wave flags (128B) with relaxed agent loads.
// One __syncthreads per tile (gates ready / As+Gs reuse); As and Gs are
// double-buffered per group (LDS = 16.9KB + 135.2KB = 152KB).
// ---------------------------------------------------------------------------
__global__ __launch_bounds__(512, 1) void lstm_persistent(
    const __bf16* __restrict__ xb,    // (T, B, D) bf16
    const float* __restrict__ W,      // (D, 4H)
    const float* __restrict__ U,      // (H, 4H)
    const float* __restrict__ bias,   // (4H)
    __bf16* __restrict__ hbuf,        // 2 * B * H bf16 (double buffer)
    float* __restrict__ hlast,        // B * H fp32
    unsigned int* __restrict__ flags) // 2048 per-wave flags (8m x 32n x 8w)
{
  const int tid = threadIdx.x;
  const int wg = blockIdx.x;          // 0..127
  const int pp = wg & 3;
  const int n_blk = wg >> 2;          // 0..31
  const int mA = pp;
  const int mB = pp + 4;
  const int wave = tid >> 6;
  const int lane = tid & 63;
  const int q = lane >> 4;     // k-quad
  const int n16 = lane & 15;   // MFMA col within 16-col tile

  __shared__ __bf16 As[2][16 * 264];   // x tiles: per group 16 x 256 (+8 pad)
  __shared__ float Gs[2][8][16][132];  // per-group per-wave gate partials

  // ---- Gate-column bases (4 gates x 2 col-halves) ----
  const int nb = n_blk * 32 + n16;
  const int c00 = nb,            c01 = nb + 16;
  const int c10 = NH + nb,       c11 = NH + nb + 16;
  const int c20 = 2 * NH + nb,   c21 = 2 * NH + nb + 16;
  const int c30 = 3 * NH + nb,   c31 = 3 * NH + nb + 16;

  // ---- Persistent B fragments (shared by both groups) ----
  const float* Wb = W + (wave * 32 + q * 8) * NG;
  bf16x8 BX00 = load_bfrag(Wb + c00), BX01 = load_bfrag(Wb + c01);
  bf16x8 BX10 = load_bfrag(Wb + c10), BX11 = load_bfrag(Wb + c11);
  bf16x8 BX20 = load_bfrag(Wb + c20), BX21 = load_bfrag(Wb + c21);
  bf16x8 BX30 = load_bfrag(Wb + c30), BX31 = load_bfrag(Wb + c31);
  const float* Ub = U + (wave * 128 + q * 8) * NG;
#define DECL_J(J)                                                       \
  bf16x8 BH00##J = load_bfrag(Ub + (J) * 32 * NG + c00);                \
  bf16x8 BH01##J = load_bfrag(Ub + (J) * 32 * NG + c01);                \
  bf16x8 BH10##J = load_bfrag(Ub + (J) * 32 * NG + c10);                \
  bf16x8 BH11##J = load_bfrag(Ub + (J) * 32 * NG + c11);                \
  bf16x8 BH20##J = load_bfrag(Ub + (J) * 32 * NG + c20);                \
  bf16x8 BH21##J = load_bfrag(Ub + (J) * 32 * NG + c21);                \
  bf16x8 BH30##J = load_bfrag(Ub + (J) * 32 * NG + c30);                \
  bf16x8 BH31##J = load_bfrag(Ub + (J) * 32 * NG + c31);
  DECL_J(0) DECL_J(1) DECL_J(2) DECL_J(3)
#undef DECL_J

  // Bias folded into wave 0's accumulator init only (partials are summed)
  const float b00 = (wave == 0) ? bias[c00] : 0.f;
  const float b01 = (wave == 0) ? bias[c01] : 0.f;
  const float b10 = (wave == 0) ? bias[c10] : 0.f;
  const float b11 = (wave == 0) ? bias[c11] : 0.f;
  const float b20 = (wave == 0) ? bias[c20] : 0.f;
  const float b21 = (wave == 0) ? bias[c21] : 0.f;
  const float b30 = (wave == 0) ? bias[c30] : 0.f;
  const float b31 = (wave == 0) ? bias[c31] : 0.f;

  // ---- Elementwise-role constants ----
  const int r_e = tid >> 5;            // 0..15 row
  const int c_e = tid & 31;            // 0..31 h-col
  const int hcol = n_blk * 32 + c_e;
  float csA = 0.0f, csB = 0.0f;

  // ---- Flag addressing: flag[(m*32+n)*8 + wave] ----
  const int fidxA = (mA * 32 + n_blk) * 8 + wave;  // my group-A flag slot
  const int fidxB = (mB * 32 + n_blk) * 8 + wave;  // my group-B flag slot
  const int fbaseA = mA * 256 + (wave << 5);       // 32 flags I poll for A
  const int fbaseB = mB * 256 + (wave << 5);       // 32 flags I poll for B

#define MFMA_(a, b, acc) __builtin_amdgcn_mfma_f32_16x16x32_bf16(a, b, acc, 0, 0, 0)
#define AL(p) __hip_atomic_load(p, __ATOMIC_RELAXED, __HIP_MEMORY_SCOPE_AGENT)

  floatx4 AC00, AC01, AC10, AC11, AC20, AC21, AC30, AC31;

  // ---- Prologue: stage x(0) for both groups ----
  {
    *(bf16x8*)(As[0] + r_e * 264 + c_e * 8) =
        ((const bf16x8*)(xb + (mA * 16 + r_e) * ND))[c_e];
    *(bf16x8*)(As[1] + r_e * 264 + c_e * 8) =
        ((const bf16x8*)(xb + (mB * 16 + r_e) * ND))[c_e];
  }
  __syncthreads();

// ---- sub-blocks -----------------------------------------------------------
#define POLL_M(FBASE)                                                   \
  {                                                                     \
    const unsigned int* fp = flags + (FBASE);                           \
    const unsigned tgt = (unsigned)t;                                   \
    while (true) {                                                      \
      unsigned v = (lane < 32) ? AL(&fp[lane]) : tgt;                   \
      if (__all((int)(v >= tgt))) break;                                \
      __builtin_amdgcn_s_sleep(1);                                      \
    }                                                                   \
    __asm__ __volatile__("" ::: "memory");                              \
  }

#define GATHER_M(MG)                                                    \
  const __bf16* hrow = hbuf + (t & 1) * (NB * NH)                       \
                     + ((MG) * 16 + n16) * NH + (wave << 7) + (q << 3); \
  union { unsigned long long u[2]; bf16x8 v; } u0, u1, u2, u3;          \
  {                                                                     \
    const unsigned long long* hp0 = (const unsigned long long*)(hrow);  \
    const unsigned long long* hp1 = (const unsigned long long*)(hrow + 32); \
    const unsigned long long* hp2 = (const unsigned long long*)(hrow + 64); \
    const unsigned long long* hp3 = (const unsigned long long*)(hrow + 96); \
    u0.u[0] = AL(hp0); u0.u[1] = AL(hp0 + 1);                           \
    u1.u[0] = AL(hp1); u1.u[1] = AL(hp1 + 1);                           \
    u2.u[0] = AL(hp2); u2.u[1] = AL(hp2 + 1);                           \
    u3.u[0] = AL(hp3); u3.u[1] = AL(hp3 + 1);                           \
  }

#define XPHASE_M(GI)                                                    \
  {                                                                     \
    const __bf16* xr = As[GI] + n16 * 264 + wave * 32 + q * 8;          \
    bf16x8 a = *(const bf16x8*)xr;                                      \
    AC00 = (floatx4){b00, b00, b00, b00}; AC01 = (floatx4){b01, b01, b01, b01}; \
    AC10 = (floatx4){b10, b10, b10, b10}; AC11 = (floatx4){b11, b11, b11, b11}; \
    AC20 = (floatx4){b20, b20, b20, b20}; AC21 = (floatx4){b21, b21, b21, b21}; \
    AC30 = (floatx4){b30, b30, b30, b30}; AC31 = (floatx4){b31, b31, b31, b31}; \
    AC00 = MFMA_(a, BX00, AC00); AC01 = MFMA_(a, BX01, AC01);           \
    AC10 = MFMA_(a, BX10, AC10); AC11 = MFMA_(a, BX11, AC11);           \
    AC20 = MFMA_(a, BX20, AC20); AC21 = MFMA_(a, BX21, AC21);           \
    AC30 = MFMA_(a, BX30, AC30); AC31 = MFMA_(a, BX31, AC31);           \
  }

#define HMFMA_M()                                                       \
  {                                                                     \
    bf16x8 a0 = u0.v, a1 = u1.v, a2 = u2.v, a3 = u3.v;                  \
    AC00 = MFMA_(a0, BH000, AC00); AC01 = MFMA_(a0, BH010, AC01);       \
    AC10 = MFMA_(a0, BH100, AC10); AC11 = MFMA_(a0, BH110, AC11);       \
    AC20 = MFMA_(a0, BH200, AC20); AC21 = MFMA_(a0, BH210, AC21);       \
    AC30 = MFMA_(a0, BH300, AC30); AC31 = MFMA_(a0, BH310, AC31);       \
    AC00 = MFMA_(a1, BH001, AC00); AC01 = MFMA_(a1, BH011, AC01);       \
    AC10 = MFMA_(a1, BH101, AC10); AC11 = MFMA_(a1, BH111, AC11);       \
    AC20 = MFMA_(a1, BH201, AC20); AC21 = MFMA_(a1, BH211, AC21);       \
    AC30 = MFMA_(a1, BH301, AC30); AC31 = MFMA_(a1, BH311, AC31);       \
    AC00 = MFMA_(a2, BH002, AC00); AC01 = MFMA_(a2, BH012, AC01);       \
    AC10 = MFMA_(a2, BH102, AC10); AC11 = MFMA_(a2, BH112, AC11);       \
    AC20 = MFMA_(a2, BH202, AC20); AC21 = MFMA_(a2, BH212, AC21);       \
    AC30 = MFMA_(a2, BH302, AC30); AC31 = MFMA_(a2, BH312, AC31);       \
    AC00 = MFMA_(a3, BH003, AC00); AC01 = MFMA_(a3, BH013, AC01);       \
    AC10 = MFMA_(a3, BH103, AC10); AC11 = MFMA_(a3, BH113, AC11);       \
    AC20 = MFMA_(a3, BH203, AC20); AC21 = MFMA_(a3, BH213, AC21);       \
    AC30 = MFMA_(a3, BH303, AC30); AC31 = MFMA_(a3, BH313, AC31);       \
  }

#define REDUCE_M(GI)                                                    \
  _Pragma("unroll")                                                     \
  for (int rr = 0; rr < 4; ++rr) {                                      \
    int row = q * 4 + rr;                                               \
    Gs[GI][wave][row][n16]       = AC00[rr];                            \
    Gs[GI][wave][row][16 + n16]  = AC01[rr];                            \
    Gs[GI][wave][row][32 + n16]  = AC10[rr];                            \
    Gs[GI][wave][row][48 + n16]  = AC11[rr];                            \
    Gs[GI][wave][row][64 + n16]  = AC20[rr];                            \
    Gs[GI][wave][row][80 + n16]  = AC21[rr];                            \
    Gs[GI][wave][row][96 + n16]  = AC30[rr];                            \
    Gs[GI][wave][row][112 + n16] = AC31[rr];                            \
  }

#define CELL_M(GI, MG, CS)                                              \
  {                                                                     \
    float xi = 0.f, xf = 0.f, xg = 0.f, xo = 0.f;                       \
    _Pragma("unroll")                                                   \
    for (int w2 = 0; w2 < 8; ++w2) {                                    \
      xi += Gs[GI][w2][r_e][c_e];                                       \
      xf += Gs[GI][w2][r_e][32 + c_e];                                  \
      xg += Gs[GI][w2][r_e][64 + c_e];                                  \
      xo += Gs[GI][w2][r_e][96 + c_e];                                  \
    }                                                                   \
    float iv = fsigmoid_(xi);                                           \
    float fv = fsigmoid_(xf);                                           \
    float gv = fsoftplus_(xg);                                          \
    float ov = fsigmoid_(xo);                                           \
    (CS) = fv * (CS) + iv * gv;                                         \
    float hv = ov * fsoftplus_(CS);                                     \
    const int grow = (MG) * 16 + r_e;                                   \
    if (t == NT - 1) {                                                  \
      hlast[grow * NH + hcol] = hv;                                     \
    } else {                                                            \
      float hn1 = __shfl_xor(hv, 1);                                    \
      __hip_bfloat162 pk;                                               \
      pk.x = (__hip_bfloat16)hv; pk.y = (__hip_bfloat16)hn1;            \
      unsigned int pw = *(unsigned int*)&pk;                            \
      unsigned int po = (unsigned int)__shfl_xor((int)pw, 2);           \
      if ((c_e & 3) == 0) {                                             \
        unsigned long long vv = ((unsigned long long)po << 32) | pw;    \
        __hip_atomic_store(                                             \
            (unsigned long long*)(hbuf + ((t + 1) & 1) * (NB * NH)      \
                                  + grow * NH + hcol),                  \
            vv, __ATOMIC_RELAXED, __HIP_MEMORY_SCOPE_AGENT);            \
      }                                                                 \
    }                                                                   \
  }

// One tile: poll -> gather issue -> x(t+1) issue -> XPHASE (overlaps gather)
// -> vmcnt(0) drain -> deferred flag release (for the OPPOSITE group's
// previous publishes) -> 32 h-MFMAs -> reduce -> S2 -> As write -> cell ->
// publish (relaxed agent stores; its flag goes out early in the next tile).
#define TILE_M(GI, MG, CS, FBASE, RELC, RELIDX, RELVAL)                 \
  {                                                                     \
    POLL_M(FBASE)                                                       \
    GATHER_M(MG)                                                        \
    bf16x8 xv;                                                          \
    if (t < NT - 1)                                                     \
      xv = ((const bf16x8*)(xb + ((t + 1) * NB + (MG) * 16 + r_e) * ND))[c_e]; \
    XPHASE_M(GI)                                                        \
    asm volatile("s_waitcnt vmcnt(0)" ::: "memory");                    \
    if ((RELC) && lane == 0)                                            \
      __hip_atomic_store(&flags[(RELIDX)], (unsigned)(RELVAL),          \
                         __ATOMIC_RELAXED, __HIP_MEMORY_SCOPE_AGENT);   \
    HMFMA_M()                                                           \
    REDUCE_M(GI)                                                        \
    __syncthreads();                                                    \
    if (t < NT - 1)                                                     \
      *(bf16x8*)(As[GI] + r_e * 264 + c_e * 8) = xv;                    \
    CELL_M(GI, MG, CS)                                                  \
  }

  for (int t = 0; t < NT; ++t) {
    // Tile A releases group-B's flag (value t, from B's t-1 publishes);
    // Tile B releases group-A's flag (value t+1, from A's t publishes).
    TILE_M(0, mA, csA, fbaseA, (t >= 1), fidxB, t)
    TILE_M(1, mB, csB, fbaseB, (t < NT - 1), fidxA, (t + 1))
  }

#undef TILE_M
#undef CELL_M
#undef REDUCE_M
#undef HMFMA_M
#undef XPHASE_M
#undef GATHER_M
#undef POLL_M
#undef AL
#undef MFMA_
}

// ---------------------------------------------------------------------------
// Kernel 3: projection head. 32 blocks x 128 thr; 4 batch rows per block.
// ---------------------------------------------------------------------------
__global__ __launch_bounds__(128) void proj_kernel(
    const float* __restrict__ hlast,
    const float* __restrict__ Wm, const float* __restrict__ bm,
    const float* __restrict__ Wv, const float* __restrict__ bv,
    const float* __restrict__ eps, float* __restrict__ out) {
  __shared__ float hs[4][NH];
  const int bb = blockIdx.x * 4;
  for (int idx = threadIdx.x; idx < 4 * NH; idx += 128)
    hs[idx >> 10][idx & (NH - 1)] = hlast[(bb + (idx >> 10)) * NH + (idx & (NH - 1))];
  __syncthreads();
  const int z = threadIdx.x;
  float am[4] = {0.f, 0.f, 0.f, 0.f};
  float av[4] = {0.f, 0.f, 0.f, 0.f};
#pragma unroll 8
  for (int k = 0; k < NH; ++k) {
    float wm = Wm[k * NZ + z];
    float wv = Wv[k * NZ + z];
#pragma unroll
    for (int r = 0; r < 4; ++r) {
      am[r] += hs[r][k] * wm;
      av[r] += hs[r][k] * wv;
    }
  }
#pragma unroll
  for (int r = 0; r < 4; ++r) {
    int b = bb + r;
    float mu = am[r] + bm[z];
    float lv = av[r] + bv[z];
    float zz = mu + eps[b * NZ + z] * expf(0.5f * lv);
    out[b * NZ + z] = mu;
    out[NB * NZ + b * NZ + z] = lv;
    out[2 * NB * NZ + b * NZ + z] = zz;
  }
}

// ---------------------------------------------------------------------------
extern "C" void kernel_launch(void* const* d_in, const int* in_sizes, int n_in,
                              void* d_out, int out_size, void* d_ws, size_t ws_size,
                              hipStream_t stream) {
  const float* x   = (const float*)d_in[0];
  const float* W   = (const float*)d_in[1];
  const float* U   = (const float*)d_in[2];
  const float* b   = (const float*)d_in[3];
  const float* Wm  = (const float*)d_in[4];
  const float* bm  = (const float*)d_in[5];
  const float* Wv  = (const float*)d_in[6];
  const float* bv  = (const float*)d_in[7];
  const float* eps = (const float*)d_in[8];

  // Workspace layout:
  //   [0,       524288)   hbuf: 2 x B x H bf16
  //   [524288,  1048576)  hlast: B x H fp32
  //   [1048576, 1056768)  flags: 2048 x u32 (8 m-groups x 32 n x 8 waves)
  //   [1056768, +33.5MB)  xb: T x B x D bf16
  char* ws = (char*)d_ws;
  __bf16* hbuf = (__bf16*)ws;
  float* hlast = (float*)(ws + 524288);
  unsigned int* flags = (unsigned int*)(ws + 1048576);
  __bf16* xb = (__bf16*)(ws + 1048576 + 8192);

  hipMemsetAsync(hbuf, 0, NB * NH * sizeof(__bf16), stream);  // h_0 = 0
  hipMemsetAsync(flags, 0, 2048 * sizeof(unsigned int), stream);

  convert_x_kernel<<<dim3((NB * NT * ND) / 4 / 256), dim3(256), 0, stream>>>(
      (const float4*)x, xb);

  void* args[] = {(void*)&xb, (void*)&W, (void*)&U, (void*)&b,
                  (void*)&hbuf, (void*)&hlast, (void*)&flags};
  hipLaunchCooperativeKernel(reinterpret_cast<void*>(lstm_persistent),
                             dim3(128), dim3(512), args, 0, stream);

  proj_kernel<<<dim3(32), dim3(128), 0, stream>>>(hlast, Wm, bm, Wv, bv, eps,
                                                  (float*)d_out);
}

// Round 4
// 2415.076 us; speedup vs baseline: 2.4707x; 2.4707x over previous
//
#include <hip/hip_runtime.h>
#include <hip/hip_bf16.h>
#include <stdint.h>

// Problem constants
#define NB 128    // batch
#define NT 512    // time steps
#define ND 256    // input dim
#define NH 1024   // hidden dim
#define NZ 128    // latent dim
#define NG 4096   // 4*NH gate width

typedef __attribute__((ext_vector_type(8))) __bf16 bf16x8;
typedef __attribute__((ext_vector_type(4))) __bf16 bf16x4;
typedef __attribute__((ext_vector_type(4))) float floatx4;

// Fast native transcendentals (v_exp_f32 / v_log_f32 / v_rcp_f32).
__device__ __forceinline__ float fsigmoid_(float x) {
  return __fdividef(1.0f, 1.0f + __expf(-x));
}
__device__ __forceinline__ float fsoftplus_(float x) {
  return fmaxf(x, 0.0f) + __logf(1.0f + __expf(-fabsf(x)));
}

// B-fragment loader: 8 fp32 rows (stride NG) -> bf16x8
__device__ __forceinline__ bf16x8 load_bfrag(const float* s) {
  bf16x8 v;
#pragma unroll
  for (int jj = 0; jj < 8; ++jj) v[jj] = (__bf16)s[jj * NG];
  return v;
}

// ---------------------------------------------------------------------------
// Kernel 1: convert x (B,T,D) fp32 -> xb (T,B,D) bf16
// ---------------------------------------------------------------------------
__global__ __launch_bounds__(256) void convert_x_kernel(
    const float4* __restrict__ x, __bf16* __restrict__ xb) {
  int i = blockIdx.x * 256 + threadIdx.x;
  int d4 = i & 63;
  int bt = i >> 6;
  int b = bt >> 9;
  int t = bt & 511;
  float4 v = x[i];
  bf16x4 o;
  o[0] = (__bf16)v.x; o[1] = (__bf16)v.y; o[2] = (__bf16)v.z; o[3] = (__bf16)v.w;
  *(bf16x4*)(xb + ((t * NB + b) * ND + d4 * 4)) = o;
}

// ---------------------------------------------------------------------------
// Kernel 2: persistent LSTM — R13: sentinel-data synchronization.
// Grid 256 WGs x 512 thr (1 WG/CU, m_blk = wg&7, n_blk = wg>>3). Clique for
// batch-group m = the 32 WGs {wg : wg&7==m}; each WG publishes a 16x32 h
// patch and gathers the full 16x1024 h row-block each step.
//
// KEY INVARIANT: h = sigmoid(o)*softplus(c) >= 0, so every published bf16
// has SIGN BIT 0. hbuf is a 4-deep ring; unwritten/retired buffers hold
// 0xFFFF (sign set). Consumers poll THE GATHER WORDS THEMSELVES:
// (w & 0x8000'8000'8000'8000) == 0 across all 32B <=> data is fresh h.
// Detect == gather: no flags, no flag RT, no publish drain on the critical
// path. Serial chain per step = publish-store visibility + one in-flight
// poll iteration (~1.5 LLC RT), down from ~4 RT in R9.
//
// Re-arm protocol (single-writer per word; WG (m,n) owns its patch in every
// buffer): at step t, after detecting full h(t), re-sentinel own patch of
// buf (t+3)&3 (which held h(t-1)). Safety: full h(t) present => every
// clique WG published h(t) => each completed gather(t-1), so h(t-1) is
// dead. Durability: __syncthreads drains vmcnt, so the step-t re-sentinel
// is durable before h(t+2) (issued after S2(t+1)) exists; since consumers
// only poll buf b for h(t') after observing h(t'-1), they can never see
// sign-clear remnants of h(t'-4). Buf ring: h(t) lives in buf t&3;
// buf0 = h(0) = zeros (memset 0), bufs 1..3 memset 0xFF.
//
// Loop: [issue x(t+1) frag load] -> poll/gather h(t) (merged) -> 32 h-MFMAs
// -> reduce Gs[t&1] -> __syncthreads (the ONLY barrier; drains last step's
// publish+reset) -> cell -> publish h(t+1) into buf (t+1)&3 -> re-sentinel
// buf (t+3)&3 -> XPHASE(t+1). No As LDS staging (x frags load direct from
// xb, 16B/lane, issued a full step early). Gs double-buffered: wave-skew
// safe because any wave is <1 barrier ahead.
// All comms = agent-scope relaxed atomics (proven R9/R10); no inline asm.
// ---------------------------------------------------------------------------
__global__ __launch_bounds__(512, 1) void lstm_persistent(
    const __bf16* __restrict__ xb,    // (T, B, D) bf16
    const float* __restrict__ W,      // (D, 4H)
    const float* __restrict__ U,      // (H, 4H)
    const float* __restrict__ bias,   // (4H)
    __bf16* __restrict__ hbuf,        // 4 * B * H bf16 (ring)
    float* __restrict__ hlast)        // B * H fp32
{
  const int tid = threadIdx.x;
  const int wg = blockIdx.x;
  const int m_blk = wg & 7;
  const int n_blk = wg >> 3;
  const int wave = tid >> 6;
  const int lane = tid & 63;
  const int q = lane >> 4;     // k-quad
  const int n16 = lane & 15;   // MFMA col within 16-col tile

  __shared__ float Gs[2][8][16][132];  // per-wave gate partials (dbuf)

#define AL(p) __hip_atomic_load(p, __ATOMIC_RELAXED, __HIP_MEMORY_SCOPE_AGENT)
#define AS(p, v) __hip_atomic_store(p, v, __ATOMIC_RELAXED, __HIP_MEMORY_SCOPE_AGENT)
#define MFMA_(a, b, acc) __builtin_amdgcn_mfma_f32_16x16x32_bf16(a, b, acc, 0, 0, 0)

  // ---- Gate-column bases (4 gates x 2 col-halves) ----
  const int nb = n_blk * 32 + n16;
  const int c00 = nb,            c01 = nb + 16;
  const int c10 = NH + nb,       c11 = NH + nb + 16;
  const int c20 = 2 * NH + nb,   c21 = 2 * NH + nb + 16;
  const int c30 = 3 * NH + nb,   c31 = 3 * NH + nb + 16;

  // ---- Persistent B fragments ----
  const float* Wb = W + (wave * 32 + q * 8) * NG;
  bf16x8 BX00 = load_bfrag(Wb + c00), BX01 = load_bfrag(Wb + c01);
  bf16x8 BX10 = load_bfrag(Wb + c10), BX11 = load_bfrag(Wb + c11);
  bf16x8 BX20 = load_bfrag(Wb + c20), BX21 = load_bfrag(Wb + c21);
  bf16x8 BX30 = load_bfrag(Wb + c30), BX31 = load_bfrag(Wb + c31);
  const float* Ub = U + (wave * 128 + q * 8) * NG;
#define DECL_J(J)                                                       \
  bf16x8 BH00##J = load_bfrag(Ub + (J) * 32 * NG + c00);                \
  bf16x8 BH01##J = load_bfrag(Ub + (J) * 32 * NG + c01);                \
  bf16x8 BH10##J = load_bfrag(Ub + (J) * 32 * NG + c10);                \
  bf16x8 BH11##J = load_bfrag(Ub + (J) * 32 * NG + c11);                \
  bf16x8 BH20##J = load_bfrag(Ub + (J) * 32 * NG + c20);                \
  bf16x8 BH21##J = load_bfrag(Ub + (J) * 32 * NG + c21);                \
  bf16x8 BH30##J = load_bfrag(Ub + (J) * 32 * NG + c30);                \
  bf16x8 BH31##J = load_bfrag(Ub + (J) * 32 * NG + c31);
  DECL_J(0) DECL_J(1) DECL_J(2) DECL_J(3)
#undef DECL_J

  // Bias folded into wave 0's accumulator init only (partials are summed)
  const float b00 = (wave == 0) ? bias[c00] : 0.f;
  const float b01 = (wave == 0) ? bias[c01] : 0.f;
  const float b10 = (wave == 0) ? bias[c10] : 0.f;
  const float b11 = (wave == 0) ? bias[c11] : 0.f;
  const float b20 = (wave == 0) ? bias[c20] : 0.f;
  const float b21 = (wave == 0) ? bias[c21] : 0.f;
  const float b30 = (wave == 0) ? bias[c30] : 0.f;
  const float b31 = (wave == 0) ? bias[c31] : 0.f;

  // ---- Elementwise-role constants ----
  const int r_e = tid >> 5;            // 0..15 row
  const int c_e = tid & 31;            // 0..31 h-col
  const int hcol = n_blk * 32 + c_e;
  const int grow = m_blk * 16 + r_e;
  float c_state = 0.0f;

  // Per-lane gather base offset (within a buffer): row m*16+n16, col w*128+q*8
  const int goff = (m_blk * 16 + n16) * NH + (wave << 7) + (q << 3);

  floatx4 AC00, AC01, AC10, AC11, AC20, AC21, AC30, AC31;
#define XPHASE_(XA)                                                     \
  {                                                                     \
    AC00 = (floatx4){b00, b00, b00, b00}; AC01 = (floatx4){b01, b01, b01, b01}; \
    AC10 = (floatx4){b10, b10, b10, b10}; AC11 = (floatx4){b11, b11, b11, b11}; \
    AC20 = (floatx4){b20, b20, b20, b20}; AC21 = (floatx4){b21, b21, b21, b21}; \
    AC30 = (floatx4){b30, b30, b30, b30}; AC31 = (floatx4){b31, b31, b31, b31}; \
    AC00 = MFMA_(XA, BX00, AC00); AC01 = MFMA_(XA, BX01, AC01);         \
    AC10 = MFMA_(XA, BX10, AC10); AC11 = MFMA_(XA, BX11, AC11);         \
    AC20 = MFMA_(XA, BX20, AC20); AC21 = MFMA_(XA, BX21, AC21);         \
    AC30 = MFMA_(XA, BX30, AC30); AC31 = MFMA_(XA, BX31, AC31);         \
  }

  // x A-fragment address for step t (16B contiguous, direct from xb)
#define XFRAG_PTR(T) (const bf16x8*)(xb + ((T) * NB + m_blk * 16 + n16) * ND \
                                     + wave * 32 + q * 8)

  // ---- Prologue: x-phase for t=0 (no LDS, no barrier needed) ----
  {
    bf16x8 x0 = *XFRAG_PTR(0);
    XPHASE_(x0)
  }

  for (int t = 0; t < NT; ++t) {
    // ---- Issue x(t+1) fragment load (consumed at end of this step) ----
    bf16x8 xv;
    if (t < NT - 1) xv = *XFRAG_PTR(t + 1);

    // ---- Merged poll+gather of h(t): sign-clear across my 32B => fresh ----
    unsigned long long w0, w1, w2, w3, w4, w5, w6, w7;
    {
      const unsigned long long* hp =
          (const unsigned long long*)(hbuf + (t & 3) * (NB * NH) + goff);
      while (true) {
        w0 = AL(hp);      w1 = AL(hp + 1);
        w2 = AL(hp + 8);  w3 = AL(hp + 9);
        w4 = AL(hp + 16); w5 = AL(hp + 17);
        w6 = AL(hp + 24); w7 = AL(hp + 25);
        unsigned long long s =
            (w0 | w1 | w2 | w3 | w4 | w5 | w6 | w7) & 0x8000800080008000ULL;
        if (__all(s == 0ULL)) break;
        __builtin_amdgcn_s_sleep(1);
      }
    }
    union { unsigned long long u[2]; bf16x8 v; } u0, u1, u2, u3;
    u0.u[0] = w0; u0.u[1] = w1; u1.u[0] = w2; u1.u[1] = w3;
    u2.u[0] = w4; u2.u[1] = w5; u3.u[0] = w6; u3.u[1] = w7;
    bf16x8 a0 = u0.v, a1 = u1.v, a2 = u2.v, a3 = u3.v;

    // ---- 32 h-MFMAs ----
    AC00 = MFMA_(a0, BH000, AC00); AC01 = MFMA_(a0, BH010, AC01);
    AC10 = MFMA_(a0, BH100, AC10); AC11 = MFMA_(a0, BH110, AC11);
    AC20 = MFMA_(a0, BH200, AC20); AC21 = MFMA_(a0, BH210, AC21);
    AC30 = MFMA_(a0, BH300, AC30); AC31 = MFMA_(a0, BH310, AC31);
    AC00 = MFMA_(a1, BH001, AC00); AC01 = MFMA_(a1, BH011, AC01);
    AC10 = MFMA_(a1, BH101, AC10); AC11 = MFMA_(a1, BH111, AC11);
    AC20 = MFMA_(a1, BH201, AC20); AC21 = MFMA_(a1, BH211, AC21);
    AC30 = MFMA_(a1, BH301, AC30); AC31 = MFMA_(a1, BH311, AC31);
    AC00 = MFMA_(a2, BH002, AC00); AC01 = MFMA_(a2, BH012, AC01);
    AC10 = MFMA_(a2, BH102, AC10); AC11 = MFMA_(a2, BH112, AC11);
    AC20 = MFMA_(a2, BH202, AC20); AC21 = MFMA_(a2, BH212, AC21);
    AC30 = MFMA_(a2, BH302, AC30); AC31 = MFMA_(a2, BH312, AC31);
    AC00 = MFMA_(a3, BH003, AC00); AC01 = MFMA_(a3, BH013, AC01);
    AC10 = MFMA_(a3, BH103, AC10); AC11 = MFMA_(a3, BH113, AC11);
    AC20 = MFMA_(a3, BH203, AC20); AC21 = MFMA_(a3, BH213, AC21);
    AC30 = MFMA_(a3, BH303, AC30); AC31 = MFMA_(a3, BH313, AC31);

    // ---- Reduction: wave partials -> Gs[t&1] ----
    const int gi = t & 1;
#pragma unroll
    for (int rr = 0; rr < 4; ++rr) {
      int row = q * 4 + rr;
      Gs[gi][wave][row][n16]       = AC00[rr];
      Gs[gi][wave][row][16 + n16]  = AC01[rr];
      Gs[gi][wave][row][32 + n16]  = AC10[rr];
      Gs[gi][wave][row][48 + n16]  = AC11[rr];
      Gs[gi][wave][row][64 + n16]  = AC20[rr];
      Gs[gi][wave][row][80 + n16]  = AC21[rr];
      Gs[gi][wave][row][96 + n16]  = AC30[rr];
      Gs[gi][wave][row][112 + n16] = AC31[rr];
    }

    // S2: the only barrier. Its implicit vmcnt drain also makes last step's
    // publish + re-sentinel stores durable before this step's publish.
    __syncthreads();

    // ---- LSTM cell ----
    {
      float xi = 0.f, xf = 0.f, xg = 0.f, xo = 0.f;
#pragma unroll
      for (int w2i = 0; w2i < 8; ++w2i) {
        xi += Gs[gi][w2i][r_e][c_e];
        xf += Gs[gi][w2i][r_e][32 + c_e];
        xg += Gs[gi][w2i][r_e][64 + c_e];
        xo += Gs[gi][w2i][r_e][96 + c_e];
      }
      float iv = fsigmoid_(xi);
      float fv = fsigmoid_(xf);
      float gv = fsoftplus_(xg);
      float ov = fsigmoid_(xo);
      c_state = fv * c_state + iv * gv;
      float hv = ov * fsoftplus_(c_state);   // hv >= 0 always: sign bit 0
      if (t == NT - 1) {
        hlast[grow * NH + hcol] = hv;
      } else {
        // 8B packed publish into buf (t+1)&3: 2x shfl_xor, lanes c_e%4==0
        float hn1 = __shfl_xor(hv, 1);
        __hip_bfloat162 pk;
        pk.x = (__hip_bfloat16)hv; pk.y = (__hip_bfloat16)hn1;
        unsigned int pw = *(unsigned int*)&pk;
        unsigned int po = (unsigned int)__shfl_xor((int)pw, 2);
        if ((c_e & 3) == 0) {
          unsigned long long vv = ((unsigned long long)po << 32) | pw;
          AS((unsigned long long*)(hbuf + ((t + 1) & 3) * (NB * NH)
                                   + grow * NH + hcol), vv);
          // Re-sentinel my patch of buf (t+3)&3 (held h(t-1), now dead).
          AS((unsigned long long*)(hbuf + ((t + 3) & 3) * (NB * NH)
                                   + grow * NH + hcol),
             0xFFFFFFFFFFFFFFFFULL);
        }
      }
    }

    // ---- Hidden work while the publish round-trips: x-GEMM for t+1 ----
    if (t < NT - 1) XPHASE_(xv)
  }
#undef XFRAG_PTR
#undef XPHASE_
#undef AS
#undef AL
#undef MFMA_
}

// ---------------------------------------------------------------------------
// Kernel 3: projection head. 32 blocks x 128 thr; 4 batch rows per block.
// ---------------------------------------------------------------------------
__global__ __launch_bounds__(128) void proj_kernel(
    const float* __restrict__ hlast,
    const float* __restrict__ Wm, const float* __restrict__ bm,
    const float* __restrict__ Wv, const float* __restrict__ bv,
    const float* __restrict__ eps, float* __restrict__ out) {
  __shared__ float hs[4][NH];
  const int bb = blockIdx.x * 4;
  for (int idx = threadIdx.x; idx < 4 * NH; idx += 128)
    hs[idx >> 10][idx & (NH - 1)] = hlast[(bb + (idx >> 10)) * NH + (idx & (NH - 1))];
  __syncthreads();
  const int z = threadIdx.x;
  float am[4] = {0.f, 0.f, 0.f, 0.f};
  float av[4] = {0.f, 0.f, 0.f, 0.f};
#pragma unroll 8
  for (int k = 0; k < NH; ++k) {
    float wm = Wm[k * NZ + z];
    float wv = Wv[k * NZ + z];
#pragma unroll
    for (int r = 0; r < 4; ++r) {
      am[r] += hs[r][k] * wm;
      av[r] += hs[r][k] * wv;
    }
  }
#pragma unroll
  for (int r = 0; r < 4; ++r) {
    int b = bb + r;
    float mu = am[r] + bm[z];
    float lv = av[r] + bv[z];
    float zz = mu + eps[b * NZ + z] * expf(0.5f * lv);
    out[b * NZ + z] = mu;
    out[NB * NZ + b * NZ + z] = lv;
    out[2 * NB * NZ + b * NZ + z] = zz;
  }
}

// ---------------------------------------------------------------------------
extern "C" void kernel_launch(void* const* d_in, const int* in_sizes, int n_in,
                              void* d_out, int out_size, void* d_ws, size_t ws_size,
                              hipStream_t stream) {
  const float* x   = (const float*)d_in[0];
  const float* W   = (const float*)d_in[1];
  const float* U   = (const float*)d_in[2];
  const float* b   = (const float*)d_in[3];
  const float* Wm  = (const float*)d_in[4];
  const float* bm  = (const float*)d_in[5];
  const float* Wv  = (const float*)d_in[6];
  const float* bv  = (const float*)d_in[7];
  const float* eps = (const float*)d_in[8];

  // Workspace layout:
  //   [0,       1048576)   hbuf: 4-deep ring of B x H bf16 (256KB each)
  //   [1048576, +33.5MB)   xb: T x B x D bf16
  //   hlast (B x H fp32, 512KB) ALIASES xb's t<8 region: x(t<8) is dead
  //   after step 7; hlast is written only at step NT-1. Keeps total
  //   workspace within the proven footprint.
  char* ws = (char*)d_ws;
  __bf16* hbuf = (__bf16*)ws;
  __bf16* xb   = (__bf16*)(ws + 1048576);
  float* hlast = (float*)(ws + 1048576);

  // buf0 = h(0) = 0 (sign-clear = "present"); bufs 1..3 = 0xFFFF sentinel.
  hipMemsetAsync(hbuf, 0, NB * NH * sizeof(__bf16), stream);
  hipMemsetAsync(hbuf + NB * NH, 0xFF, 3 * NB * NH * sizeof(__bf16), stream);

  convert_x_kernel<<<dim3((NB * NT * ND) / 4 / 256), dim3(256), 0, stream>>>(
      (const float4*)x, xb);

  void* args[] = {(void*)&xb, (void*)&W, (void*)&U, (void*)&b,
                  (void*)&hbuf, (void*)&hlast};
  hipLaunchCooperativeKernel(reinterpret_cast<void*>(lstm_persistent),
                             dim3(256), dim3(512), args, 0, stream);

  proj_kernel<<<dim3(32), dim3(128), 0, stream>>>(hlast, Wm, bm, Wv, bv, eps,
                                                  (float*)d_out);
}

// Round 5
// 2342.153 us; speedup vs baseline: 2.5476x; 1.0311x over previous
//
#include <hip/hip_runtime.h>
#include <hip/hip_bf16.h>
#include <stdint.h>

// Problem constants
#define NB 128    // batch
#define NT 512    // time steps
#define ND 256    // input dim
#define NH 1024   // hidden dim
#define NZ 128    // latent dim
#define NG 4096   // 4*NH gate width

typedef __attribute__((ext_vector_type(8))) __bf16 bf16x8;
typedef __attribute__((ext_vector_type(4))) __bf16 bf16x4;
typedef __attribute__((ext_vector_type(4))) float floatx4;

// Fast native transcendentals (v_exp_f32 / v_log_f32 / v_rcp_f32).
__device__ __forceinline__ float fsigmoid_(float x) {
  return __fdividef(1.0f, 1.0f + __expf(-x));
}
__device__ __forceinline__ float fsoftplus_(float x) {
  return fmaxf(x, 0.0f) + __logf(1.0f + __expf(-fabsf(x)));
}

// B-fragment loader: 8 fp32 rows (stride NG) -> bf16x8
__device__ __forceinline__ bf16x8 load_bfrag(const float* s) {
  bf16x8 v;
#pragma unroll
  for (int jj = 0; jj < 8; ++jj) v[jj] = (__bf16)s[jj * NG];
  return v;
}

// ---------------------------------------------------------------------------
// Kernel 1: convert x (B,T,D) fp32 -> xb (T,B,D) bf16
// ---------------------------------------------------------------------------
__global__ __launch_bounds__(256) void convert_x_kernel(
    const float4* __restrict__ x, __bf16* __restrict__ xb) {
  int i = blockIdx.x * 256 + threadIdx.x;
  int d4 = i & 63;
  int bt = i >> 6;
  int b = bt >> 9;
  int t = bt & 511;
  float4 v = x[i];
  bf16x4 o;
  o[0] = (__bf16)v.x; o[1] = (__bf16)v.y; o[2] = (__bf16)v.z; o[3] = (__bf16)v.w;
  *(bf16x4*)(xb + ((t * NB + b) * ND + d4 * 4)) = o;
}

// ---------------------------------------------------------------------------
// Kernel 2: persistent LSTM — R14: sentinel sync + lazy re-poll.
// (R13 structure, one change: the merged poll/gather reloads ONLY words
// that still read as sentinel.)
//
// Grid 256 WGs x 512 thr (1 WG/CU, m_blk = wg&7, n_blk = wg>>3). Clique for
// batch-group m = the 32 WGs {wg : wg&7==m}; each WG publishes a 16x32 h
// patch and gathers the full 16x1024 h row-block each step.
//
// KEY INVARIANT: h = sigmoid(o)*softplus(c) >= 0, so every published bf16
// has SIGN BIT 0. hbuf is a 4-deep ring; unwritten/retired buffers hold
// 0xFFFF (sign set). Consumers poll THE GATHER WORDS THEMSELVES:
// (w & 0x8000'8000'8000'8000) == 0 <=> that 8B word is fresh h. Each 8B
// word is single-writer-atomic and single-assignment per ring slot per
// step, so once a word reads fresh its value is FINAL — lanes reload only
// words still showing sentinel. First iteration loads all 8; steady-state
// retries touch only stragglers. This kills the LLC poll-BW congestion
// (R13 re-swept 32KB/WG/iteration; ~8MB device-wide per sweep).
//
// Re-arm protocol (single-writer per word; WG (m,n) owns its patch in every
// buffer): at step t, after detecting full h(t), re-sentinel own patch of
// buf (t+3)&3 (which held h(t-1)). Safety: full h(t) present => every
// clique WG published h(t) => each completed gather(t-1), so h(t-1) is
// dead. Durability: __syncthreads drains vmcnt, so the step-t re-sentinel
// is durable before h(t+2) (issued after S2(t+1)) exists. Buf ring: h(t)
// lives in buf t&3; buf0 = h(0) = zeros, bufs 1..3 memset 0xFF.
//
// Loop: [issue x(t+1) frag load] -> lazy poll/gather h(t) -> 32 h-MFMAs
// -> reduce Gs[t&1] -> __syncthreads (ONLY barrier) -> cell -> publish
// h(t+1) -> re-sentinel buf (t+3)&3 -> XPHASE(t+1). No As LDS staging.
// All comms = agent-scope relaxed atomics; no inline asm.
// ---------------------------------------------------------------------------
__global__ __launch_bounds__(512, 1) void lstm_persistent(
    const __bf16* __restrict__ xb,    // (T, B, D) bf16
    const float* __restrict__ W,      // (D, 4H)
    const float* __restrict__ U,      // (H, 4H)
    const float* __restrict__ bias,   // (4H)
    __bf16* __restrict__ hbuf,        // 4 * B * H bf16 (ring)
    float* __restrict__ hlast)        // B * H fp32
{
  const int tid = threadIdx.x;
  const int wg = blockIdx.x;
  const int m_blk = wg & 7;
  const int n_blk = wg >> 3;
  const int wave = tid >> 6;
  const int lane = tid & 63;
  const int q = lane >> 4;     // k-quad
  const int n16 = lane & 15;   // MFMA col within 16-col tile

  __shared__ float Gs[2][8][16][132];  // per-wave gate partials (dbuf)

#define AL(p) __hip_atomic_load(p, __ATOMIC_RELAXED, __HIP_MEMORY_SCOPE_AGENT)
#define AS(p, v) __hip_atomic_store(p, v, __ATOMIC_RELAXED, __HIP_MEMORY_SCOPE_AGENT)
#define MFMA_(a, b, acc) __builtin_amdgcn_mfma_f32_16x16x32_bf16(a, b, acc, 0, 0, 0)

  // ---- Gate-column bases (4 gates x 2 col-halves) ----
  const int nb = n_blk * 32 + n16;
  const int c00 = nb,            c01 = nb + 16;
  const int c10 = NH + nb,       c11 = NH + nb + 16;
  const int c20 = 2 * NH + nb,   c21 = 2 * NH + nb + 16;
  const int c30 = 3 * NH + nb,   c31 = 3 * NH + nb + 16;

  // ---- Persistent B fragments ----
  const float* Wb = W + (wave * 32 + q * 8) * NG;
  bf16x8 BX00 = load_bfrag(Wb + c00), BX01 = load_bfrag(Wb + c01);
  bf16x8 BX10 = load_bfrag(Wb + c10), BX11 = load_bfrag(Wb + c11);
  bf16x8 BX20 = load_bfrag(Wb + c20), BX21 = load_bfrag(Wb + c21);
  bf16x8 BX30 = load_bfrag(Wb + c30), BX31 = load_bfrag(Wb + c31);
  const float* Ub = U + (wave * 128 + q * 8) * NG;
#define DECL_J(J)                                                       \
  bf16x8 BH00##J = load_bfrag(Ub + (J) * 32 * NG + c00);                \
  bf16x8 BH01##J = load_bfrag(Ub + (J) * 32 * NG + c01);                \
  bf16x8 BH10##J = load_bfrag(Ub + (J) * 32 * NG + c10);                \
  bf16x8 BH11##J = load_bfrag(Ub + (J) * 32 * NG + c11);                \
  bf16x8 BH20##J = load_bfrag(Ub + (J) * 32 * NG + c20);                \
  bf16x8 BH21##J = load_bfrag(Ub + (J) * 32 * NG + c21);                \
  bf16x8 BH30##J = load_bfrag(Ub + (J) * 32 * NG + c30);                \
  bf16x8 BH31##J = load_bfrag(Ub + (J) * 32 * NG + c31);
  DECL_J(0) DECL_J(1) DECL_J(2) DECL_J(3)
#undef DECL_J

  // Bias folded into wave 0's accumulator init only (partials are summed)
  const float b00 = (wave == 0) ? bias[c00] : 0.f;
  const float b01 = (wave == 0) ? bias[c01] : 0.f;
  const float b10 = (wave == 0) ? bias[c10] : 0.f;
  const float b11 = (wave == 0) ? bias[c11] : 0.f;
  const float b20 = (wave == 0) ? bias[c20] : 0.f;
  const float b21 = (wave == 0) ? bias[c21] : 0.f;
  const float b30 = (wave == 0) ? bias[c30] : 0.f;
  const float b31 = (wave == 0) ? bias[c31] : 0.f;

  // ---- Elementwise-role constants ----
  const int r_e = tid >> 5;            // 0..15 row
  const int c_e = tid & 31;            // 0..31 h-col
  const int hcol = n_blk * 32 + c_e;
  const int grow = m_blk * 16 + r_e;
  float c_state = 0.0f;

  // Per-lane gather base offset (within a buffer): row m*16+n16, col w*128+q*8
  const int goff = (m_blk * 16 + n16) * NH + (wave << 7) + (q << 3);

  floatx4 AC00, AC01, AC10, AC11, AC20, AC21, AC30, AC31;
#define XPHASE_(XA)                                                     \
  {                                                                     \
    AC00 = (floatx4){b00, b00, b00, b00}; AC01 = (floatx4){b01, b01, b01, b01}; \
    AC10 = (floatx4){b10, b10, b10, b10}; AC11 = (floatx4){b11, b11, b11, b11}; \
    AC20 = (floatx4){b20, b20, b20, b20}; AC21 = (floatx4){b21, b21, b21, b21}; \
    AC30 = (floatx4){b30, b30, b30, b30}; AC31 = (floatx4){b31, b31, b31, b31}; \
    AC00 = MFMA_(XA, BX00, AC00); AC01 = MFMA_(XA, BX01, AC01);         \
    AC10 = MFMA_(XA, BX10, AC10); AC11 = MFMA_(XA, BX11, AC11);         \
    AC20 = MFMA_(XA, BX20, AC20); AC21 = MFMA_(XA, BX21, AC21);         \
    AC30 = MFMA_(XA, BX30, AC30); AC31 = MFMA_(XA, BX31, AC31);         \
  }

  // x A-fragment address for step t (16B contiguous, direct from xb)
#define XFRAG_PTR(T) (const bf16x8*)(xb + ((T) * NB + m_blk * 16 + n16) * ND \
                                     + wave * 32 + q * 8)

  // ---- Prologue: x-phase for t=0 (no LDS, no barrier needed) ----
  {
    bf16x8 x0 = *XFRAG_PTR(0);
    XPHASE_(x0)
  }

  const unsigned long long SGN = 0x8000800080008000ULL;

  for (int t = 0; t < NT; ++t) {
    // ---- Issue x(t+1) fragment load (consumed at end of this step) ----
    bf16x8 xv;
    if (t < NT - 1) xv = *XFRAG_PTR(t + 1);

    // ---- Lazy poll+gather of h(t): reload ONLY words still sentinel ----
    unsigned long long w0 = SGN, w1 = SGN, w2 = SGN, w3 = SGN,
                       w4 = SGN, w5 = SGN, w6 = SGN, w7 = SGN;
    {
      const unsigned long long* hp =
          (const unsigned long long*)(hbuf + (t & 3) * (NB * NH) + goff);
      while (true) {
        if (w0 & SGN) w0 = AL(hp);
        if (w1 & SGN) w1 = AL(hp + 1);
        if (w2 & SGN) w2 = AL(hp + 8);
        if (w3 & SGN) w3 = AL(hp + 9);
        if (w4 & SGN) w4 = AL(hp + 16);
        if (w5 & SGN) w5 = AL(hp + 17);
        if (w6 & SGN) w6 = AL(hp + 24);
        if (w7 & SGN) w7 = AL(hp + 25);
        unsigned long long s =
            (w0 | w1 | w2 | w3 | w4 | w5 | w6 | w7) & SGN;
        if (__all(s == 0ULL)) break;
        __builtin_amdgcn_s_sleep(1);
      }
    }
    union { unsigned long long u[2]; bf16x8 v; } u0, u1, u2, u3;
    u0.u[0] = w0; u0.u[1] = w1; u1.u[0] = w2; u1.u[1] = w3;
    u2.u[0] = w4; u2.u[1] = w5; u3.u[0] = w6; u3.u[1] = w7;
    bf16x8 a0 = u0.v, a1 = u1.v, a2 = u2.v, a3 = u3.v;

    // ---- 32 h-MFMAs ----
    AC00 = MFMA_(a0, BH000, AC00); AC01 = MFMA_(a0, BH010, AC01);
    AC10 = MFMA_(a0, BH100, AC10); AC11 = MFMA_(a0, BH110, AC11);
    AC20 = MFMA_(a0, BH200, AC20); AC21 = MFMA_(a0, BH210, AC21);
    AC30 = MFMA_(a0, BH300, AC30); AC31 = MFMA_(a0, BH310, AC31);
    AC00 = MFMA_(a1, BH001, AC00); AC01 = MFMA_(a1, BH011, AC01);
    AC10 = MFMA_(a1, BH101, AC10); AC11 = MFMA_(a1, BH111, AC11);
    AC20 = MFMA_(a1, BH201, AC20); AC21 = MFMA_(a1, BH211, AC21);
    AC30 = MFMA_(a1, BH301, AC30); AC31 = MFMA_(a1, BH311, AC31);
    AC00 = MFMA_(a2, BH002, AC00); AC01 = MFMA_(a2, BH012, AC01);
    AC10 = MFMA_(a2, BH102, AC10); AC11 = MFMA_(a2, BH112, AC11);
    AC20 = MFMA_(a2, BH202, AC20); AC21 = MFMA_(a2, BH212, AC21);
    AC30 = MFMA_(a2, BH302, AC30); AC31 = MFMA_(a2, BH312, AC31);
    AC00 = MFMA_(a3, BH003, AC00); AC01 = MFMA_(a3, BH013, AC01);
    AC10 = MFMA_(a3, BH103, AC10); AC11 = MFMA_(a3, BH113, AC11);
    AC20 = MFMA_(a3, BH203, AC20); AC21 = MFMA_(a3, BH213, AC21);
    AC30 = MFMA_(a3, BH303, AC30); AC31 = MFMA_(a3, BH313, AC31);

    // ---- Reduction: wave partials -> Gs[t&1] ----
    const int gi = t & 1;
#pragma unroll
    for (int rr = 0; rr < 4; ++rr) {
      int row = q * 4 + rr;
      Gs[gi][wave][row][n16]       = AC00[rr];
      Gs[gi][wave][row][16 + n16]  = AC01[rr];
      Gs[gi][wave][row][32 + n16]  = AC10[rr];
      Gs[gi][wave][row][48 + n16]  = AC11[rr];
      Gs[gi][wave][row][64 + n16]  = AC20[rr];
      Gs[gi][wave][row][80 + n16]  = AC21[rr];
      Gs[gi][wave][row][96 + n16]  = AC30[rr];
      Gs[gi][wave][row][112 + n16] = AC31[rr];
    }

    // S2: the only barrier. Its implicit vmcnt drain also makes last step's
    // publish + re-sentinel stores durable before this step's publish.
    __syncthreads();

    // ---- LSTM cell ----
    {
      float xi = 0.f, xf = 0.f, xg = 0.f, xo = 0.f;
#pragma unroll
      for (int w2i = 0; w2i < 8; ++w2i) {
        xi += Gs[gi][w2i][r_e][c_e];
        xf += Gs[gi][w2i][r_e][32 + c_e];
        xg += Gs[gi][w2i][r_e][64 + c_e];
        xo += Gs[gi][w2i][r_e][96 + c_e];
      }
      float iv = fsigmoid_(xi);
      float fv = fsigmoid_(xf);
      float gv = fsoftplus_(xg);
      float ov = fsigmoid_(xo);
      c_state = fv * c_state + iv * gv;
      float hv = ov * fsoftplus_(c_state);   // hv >= 0 always: sign bit 0
      if (t == NT - 1) {
        hlast[grow * NH + hcol] = hv;
      } else {
        // 8B packed publish into buf (t+1)&3: 2x shfl_xor, lanes c_e%4==0
        float hn1 = __shfl_xor(hv, 1);
        __hip_bfloat162 pk;
        pk.x = (__hip_bfloat16)hv; pk.y = (__hip_bfloat16)hn1;
        unsigned int pw = *(unsigned int*)&pk;
        unsigned int po = (unsigned int)__shfl_xor((int)pw, 2);
        if ((c_e & 3) == 0) {
          unsigned long long vv = ((unsigned long long)po << 32) | pw;
          AS((unsigned long long*)(hbuf + ((t + 1) & 3) * (NB * NH)
                                   + grow * NH + hcol), vv);
          // Re-sentinel my patch of buf (t+3)&3 (held h(t-1), now dead).
          AS((unsigned long long*)(hbuf + ((t + 3) & 3) * (NB * NH)
                                   + grow * NH + hcol),
             0xFFFFFFFFFFFFFFFFULL);
        }
      }
    }

    // ---- Hidden work while the publish round-trips: x-GEMM for t+1 ----
    if (t < NT - 1) XPHASE_(xv)
  }
#undef XFRAG_PTR
#undef XPHASE_
#undef AS
#undef AL
#undef MFMA_
}

// ---------------------------------------------------------------------------
// Kernel 3: projection head. 32 blocks x 128 thr; 4 batch rows per block.
// ---------------------------------------------------------------------------
__global__ __launch_bounds__(128) void proj_kernel(
    const float* __restrict__ hlast,
    const float* __restrict__ Wm, const float* __restrict__ bm,
    const float* __restrict__ Wv, const float* __restrict__ bv,
    const float* __restrict__ eps, float* __restrict__ out) {
  __shared__ float hs[4][NH];
  const int bb = blockIdx.x * 4;
  for (int idx = threadIdx.x; idx < 4 * NH; idx += 128)
    hs[idx >> 10][idx & (NH - 1)] = hlast[(bb + (idx >> 10)) * NH + (idx & (NH - 1))];
  __syncthreads();
  const int z = threadIdx.x;
  float am[4] = {0.f, 0.f, 0.f, 0.f};
  float av[4] = {0.f, 0.f, 0.f, 0.f};
#pragma unroll 8
  for (int k = 0; k < NH; ++k) {
    float wm = Wm[k * NZ + z];
    float wv = Wv[k * NZ + z];
#pragma unroll
    for (int r = 0; r < 4; ++r) {
      am[r] += hs[r][k] * wm;
      av[r] += hs[r][k] * wv;
    }
  }
#pragma unroll
  for (int r = 0; r < 4; ++r) {
    int b = bb + r;
    float mu = am[r] + bm[z];
    float lv = av[r] + bv[z];
    float zz = mu + eps[b * NZ + z] * expf(0.5f * lv);
    out[b * NZ + z] = mu;
    out[NB * NZ + b * NZ + z] = lv;
    out[2 * NB * NZ + b * NZ + z] = zz;
  }
}

// ---------------------------------------------------------------------------
extern "C" void kernel_launch(void* const* d_in, const int* in_sizes, int n_in,
                              void* d_out, int out_size, void* d_ws, size_t ws_size,
                              hipStream_t stream) {
  const float* x   = (const float*)d_in[0];
  const float* W   = (const float*)d_in[1];
  const float* U   = (const float*)d_in[2];
  const float* b   = (const float*)d_in[3];
  const float* Wm  = (const float*)d_in[4];
  const float* bm  = (const float*)d_in[5];
  const float* Wv  = (const float*)d_in[6];
  const float* bv  = (const float*)d_in[7];
  const float* eps = (const float*)d_in[8];

  // Workspace layout:
  //   [0,       1048576)   hbuf: 4-deep ring of B x H bf16 (256KB each)
  //   [1048576, +33.5MB)   xb: T x B x D bf16
  //   hlast (B x H fp32, 512KB) ALIASES xb's t<8 region: x(t<8) is dead
  //   after step 7; hlast is written only at step NT-1.
  char* ws = (char*)d_ws;
  __bf16* hbuf = (__bf16*)ws;
  __bf16* xb   = (__bf16*)(ws + 1048576);
  float* hlast = (float*)(ws + 1048576);

  // buf0 = h(0) = 0 (sign-clear = "present"); bufs 1..3 = 0xFFFF sentinel.
  hipMemsetAsync(hbuf, 0, NB * NH * sizeof(__bf16), stream);
  hipMemsetAsync(hbuf + NB * NH, 0xFF, 3 * NB * NH * sizeof(__bf16), stream);

  convert_x_kernel<<<dim3((NB * NT * ND) / 4 / 256), dim3(256), 0, stream>>>(
      (const float4*)x, xb);

  void* args[] = {(void*)&xb, (void*)&W, (void*)&U, (void*)&b,
                  (void*)&hbuf, (void*)&hlast};
  hipLaunchCooperativeKernel(reinterpret_cast<void*>(lstm_persistent),
                             dim3(256), dim3(512), args, 0, stream);

  proj_kernel<<<dim3(32), dim3(128), 0, stream>>>(hlast, Wm, bm, Wv, bv, eps,
                                                  (float*)d_out);
}